// Round 1
// baseline (520.375 us; speedup 1.0000x reference)
//
#include <hip/hip_runtime.h>

namespace {
constexpr int kB = 4096;
constexpr int kC = 10000;
constexpr int kC4 = kC / 4;   // 2500 float4 chunks per row
constexpr int kNT = 256;      // threads per block
}

// ---------- wave(64)-level helpers ----------
__device__ __forceinline__ float wave_sum(float v) {
#pragma unroll
  for (int o = 32; o > 0; o >>= 1) v += __shfl_down(v, o, 64);
  return v;
}

__device__ __forceinline__ double wave_sum_d(double v) {
#pragma unroll
  for (int o = 32; o > 0; o >>= 1) v += __shfl_down(v, o, 64);
  return v;
}

__device__ __forceinline__ float wave_max(float v) {
#pragma unroll
  for (int o = 32; o > 0; o >>= 1) v = fmaxf(v, __shfl_down(v, o, 64));
  return v;
}

// merge top-2 pairs across a wave
__device__ __forceinline__ void wave_top2(float& m1, float& m2) {
#pragma unroll
  for (int o = 32; o > 0; o >>= 1) {
    float a1 = __shfl_down(m1, o, 64);
    float a2 = __shfl_down(m2, o, 64);
    float lo = fminf(m1, a1);
    m1 = fmaxf(m1, a1);
    m2 = fmaxf(lo, fmaxf(m2, a2));
  }
}

// One block per sample row. Computes per-row ce, rowB = sum_t thr_t*tval_t*(kd_t-ce),
// and rowmax = max over the three real teachers' row maxima.
__global__ __launch_bounds__(kNT) void mt3_row_kernel(
    const float* __restrict__ g1, const float* __restrict__ g2,
    const float* __restrict__ g3, const float* __restrict__ gs,
    const int* __restrict__ gt,
    float* __restrict__ ceArr, float* __restrict__ bArr,
    float* __restrict__ mArr) {
  const int b = blockIdx.x;
  const int tid = threadIdx.x;
  const int lane = tid & 63;
  const int wv = tid >> 6;  // 4 waves

  const float4* __restrict__ p1 = reinterpret_cast<const float4*>(g1 + (size_t)b * kC);
  const float4* __restrict__ p2 = reinterpret_cast<const float4*>(g2 + (size_t)b * kC);
  const float4* __restrict__ p3 = reinterpret_cast<const float4*>(g3 + (size_t)b * kC);
  const float4* __restrict__ ps = reinterpret_cast<const float4*>(gs + (size_t)b * kC);

  const int target = gt[b];
  const int tchunk = target >> 2;
  const int tsub = target & 3;

  // per-teacher state: 0..2 real teachers, 3 = mimic
  float m1[4], m2[4], Z[4], D[4];
#pragma unroll
  for (int t = 0; t < 4; t++) { m1[t] = -1e30f; m2[t] = -1e30f; Z[t] = 0.f; D[t] = 0.f; }
  float Z1 = 0.f;   // sum exp(s)      (T=1, for CE logsumexp)
  float Z20 = 0.f;  // sum exp(s/20)   (T=20, for KD logsumexp)

  __shared__ float s_tval[5];            // teacher/student values at target column
  __shared__ float sZ[4][4], sD[4][4], sM1[4][4], sM2[4][4], sZ1[4], sZ20[4];

  for (int c = tid; c < kC4; c += kNT) {
    float4 A = p1[c];
    float4 Bv = p2[c];
    float4 Cv = p3[c];
    float4 Sv = ps[c];
    float va[4] = {A.x, A.y, A.z, A.w};
    float vb[4] = {Bv.x, Bv.y, Bv.z, Bv.w};
    float vc[4] = {Cv.x, Cv.y, Cv.z, Cv.w};
    float vs[4] = {Sv.x, Sv.y, Sv.z, Sv.w};
#pragma unroll
    for (int j = 0; j < 4; j++) {
      const float mim = (va[j] + vb[j] + vc[j]) * (1.0f / 3.0f);
      const float tv[4] = {va[j], vb[j], vc[j], mim};
      const float sv = vs[j];
#pragma unroll
      for (int t = 0; t < 4; t++) {
        const float x = tv[t];
        // branchless top-2 update
        const float lo = fminf(x, m1[t]);
        m1[t] = fmaxf(x, m1[t]);
        m2[t] = fmaxf(m2[t], lo);
        // inputs are N(0,1): exp(x/20) cannot overflow; no max subtraction needed
        const float e = __expf(x * 0.05f);
        Z[t] += e;
        D[t] = fmaf(e, sv, D[t]);
      }
      Z1 += __expf(sv);
      Z20 += __expf(sv * 0.05f);
      if (c == tchunk && j == tsub) {
        // record target-column values bitwise-consistently with max tracking
        s_tval[0] = va[j]; s_tval[1] = vb[j]; s_tval[2] = vc[j];
        s_tval[3] = mim;   s_tval[4] = sv;
      }
    }
  }

  // wave-level reductions
#pragma unroll
  for (int t = 0; t < 4; t++) {
    Z[t] = wave_sum(Z[t]);
    D[t] = wave_sum(D[t]);
    wave_top2(m1[t], m2[t]);
  }
  Z1 = wave_sum(Z1);
  Z20 = wave_sum(Z20);

  if (lane == 0) {
#pragma unroll
    for (int t = 0; t < 4; t++) {
      sZ[t][wv] = Z[t]; sD[t][wv] = D[t];
      sM1[t][wv] = m1[t]; sM2[t][wv] = m2[t];
    }
    sZ1[wv] = Z1; sZ20[wv] = Z20;
  }
  __syncthreads();

  if (tid == 0) {
    float fZ[4], fD[4], fM1[4], fM2[4];
    float fZ1 = 0.f, fZ20 = 0.f;
#pragma unroll
    for (int t = 0; t < 4; t++) { fZ[t] = 0.f; fD[t] = 0.f; fM1[t] = -1e30f; fM2[t] = -1e30f; }
#pragma unroll
    for (int w = 0; w < 4; w++) {
      fZ1 += sZ1[w]; fZ20 += sZ20[w];
#pragma unroll
      for (int t = 0; t < 4; t++) {
        fZ[t] += sZ[t][w];
        fD[t] += sD[t][w];
        const float a1 = sM1[t][w], a2 = sM2[t][w];
        const float lo = fminf(fM1[t], a1);
        fM1[t] = fmaxf(fM1[t], a1);
        fM2[t] = fmaxf(lo, fmaxf(fM2[t], a2));
      }
    }

    const float sval = s_tval[4];
    const float ce = logf(fZ1) - sval;        // logsumexp(out_s) - out_s[target]
    const float lz20 = logf(fZ20);            // log sum exp(out_s/20)

    float d[4], kd[4], tval[4];
#pragma unroll
    for (int t = 0; t < 4; t++) {
      tval[t] = s_tval[t];
      // kd = T^2 * ( logZ_s20 - (sum_c p_c * s_c)/T ),  p from teacher softmax at T=20
      kd[t] = 400.0f * (lz20 - fD[t] / (20.0f * fZ[t]));
      d[t] = (tval[t] == fM1[t]) ? (fM1[t] - fM2[t]) : 0.0f;
    }
    // out_threshold = softmax(d / 2)
    float ew[4], se = 0.f;
#pragma unroll
    for (int t = 0; t < 4; t++) { ew[t] = __expf(d[t] * 0.5f); se += ew[t]; }
    float rowB = 0.f;
#pragma unroll
    for (int t = 0; t < 4; t++) rowB += (ew[t] / se) * tval[t] * (kd[t] - ce);

    ceArr[b] = ce;
    bArr[b] = rowB;
    mArr[b] = fmaxf(fM1[0], fmaxf(fM1[1], fM1[2]));  // real teachers only
  }
}

// Single-block reduction of the 3 per-row arrays -> scalar output.
__global__ __launch_bounds__(256) void mt3_finalize(
    const float* __restrict__ ceArr, const float* __restrict__ bArr,
    const float* __restrict__ mArr, float* __restrict__ out) {
  const int tid = threadIdx.x;
  const int lane = tid & 63;
  const int wv = tid >> 6;

  double sc = 0.0, sb = 0.0;
  float mx = -1e30f;
  for (int i = tid; i < kB; i += 256) {
    sc += (double)ceArr[i];
    sb += (double)bArr[i];
    mx = fmaxf(mx, mArr[i]);
  }
  sc = wave_sum_d(sc);
  sb = wave_sum_d(sb);
  mx = wave_max(mx);

  __shared__ double dsc[4], dsb[4];
  __shared__ float dmx[4];
  if (lane == 0) { dsc[wv] = sc; dsb[wv] = sb; dmx[wv] = mx; }
  __syncthreads();
  if (tid == 0) {
    double A = 0.0, Bc = 0.0;
    float M = -1e30f;
#pragma unroll
    for (int w = 0; w < 4; w++) { A += dsc[w]; Bc += dsb[w]; M = fmaxf(M, dmx[w]); }
    // mean(ce) + (alpha/max_preds) * mean(rowB)
    out[0] = (float)((A + 0.8 * Bc / (double)M) / (double)kB);
  }
}

extern "C" void kernel_launch(void* const* d_in, const int* in_sizes, int n_in,
                              void* d_out, int out_size, void* d_ws, size_t ws_size,
                              hipStream_t stream) {
  const float* o1 = (const float*)d_in[0];
  const float* o2 = (const float*)d_in[1];
  const float* o3 = (const float*)d_in[2];
  const float* os = (const float*)d_in[3];
  const int* tg = (const int*)d_in[4];

  float* ws = (float*)d_ws;
  float* ceArr = ws;            // [kB]
  float* bArr = ws + kB;        // [kB]
  float* mArr = ws + 2 * kB;    // [kB]

  mt3_row_kernel<<<kB, kNT, 0, stream>>>(o1, o2, o3, os, tg, ceArr, bArr, mArr);
  mt3_finalize<<<1, 256, 0, stream>>>(ceArr, bArr, mArr, (float*)d_out);
}

// Round 2
// 517.335 us; speedup vs baseline: 1.0059x; 1.0059x over previous
//
#include <hip/hip_runtime.h>

namespace {
constexpr int kB = 4096;
constexpr int kC = 10000;
constexpr int kC4 = kC / 4;   // 2500 float4 chunks per row
constexpr int kNT = 256;      // threads per block
}

// ---------- wave(64)-level helpers ----------
__device__ __forceinline__ float wave_sum(float v) {
#pragma unroll
  for (int o = 32; o > 0; o >>= 1) v += __shfl_down(v, o, 64);
  return v;
}

__device__ __forceinline__ double wave_sum_d(double v) {
#pragma unroll
  for (int o = 32; o > 0; o >>= 1) v += __shfl_down(v, o, 64);
  return v;
}

__device__ __forceinline__ float wave_max(float v) {
#pragma unroll
  for (int o = 32; o > 0; o >>= 1) v = fmaxf(v, __shfl_down(v, o, 64));
  return v;
}

// merge top-2 pairs across a wave
__device__ __forceinline__ void wave_top2(float& m1, float& m2) {
#pragma unroll
  for (int o = 32; o > 0; o >>= 1) {
    float a1 = __shfl_down(m1, o, 64);
    float a2 = __shfl_down(m2, o, 64);
    float lo = fminf(m1, a1);
    m1 = fmaxf(m1, a1);
    m2 = fmaxf(lo, fmaxf(m2, a2));
  }
}

// One block per sample row. Computes per-row ce, rowB = sum_t thr_t*tval_t*(kd_t-ce),
// and rowmax = max over the three real teachers' row maxima.
// __launch_bounds__(256,4): allow up to 128 VGPRs so the 1-deep prefetch
// pipeline (2 x 16 VGPRs of float4 payload) fits without spilling.
__global__ __launch_bounds__(kNT, 4) void mt3_row_kernel(
    const float* __restrict__ g1, const float* __restrict__ g2,
    const float* __restrict__ g3, const float* __restrict__ gs,
    const int* __restrict__ gt,
    float* __restrict__ ceArr, float* __restrict__ bArr,
    float* __restrict__ mArr) {
  const int b = blockIdx.x;
  const int tid = threadIdx.x;
  const int lane = tid & 63;
  const int wv = tid >> 6;  // 4 waves

  const size_t rowOff = (size_t)b * kC;
  const float4* __restrict__ p1 = reinterpret_cast<const float4*>(g1 + rowOff);
  const float4* __restrict__ p2 = reinterpret_cast<const float4*>(g2 + rowOff);
  const float4* __restrict__ p3 = reinterpret_cast<const float4*>(g3 + rowOff);
  const float4* __restrict__ ps = reinterpret_cast<const float4*>(gs + rowOff);

  const int target = gt[b];

  // Target-column values, loaded once by thread 0 (bitwise-identical to the
  // raw values the loop streams through, so the == max comparison is exact).
  float tv1 = 0.f, tv2 = 0.f, tv3 = 0.f, tvs = 0.f;
  if (tid == 0) {
    tv1 = g1[rowOff + target];
    tv2 = g2[rowOff + target];
    tv3 = g3[rowOff + target];
    tvs = gs[rowOff + target];
  }

  // per-teacher state: 0..2 real teachers, 3 = mimic
  float m1[4], m2[4], Z[4], D[4];
#pragma unroll
  for (int t = 0; t < 4; t++) { m1[t] = -1e30f; m2[t] = -1e30f; Z[t] = 0.f; D[t] = 0.f; }
  float Z1 = 0.f;   // sum exp(s)      (T=1, for CE logsumexp)
  float Z20 = 0.f;  // sum exp(s/20)   (T=20, for KD logsumexp)

  __shared__ float sZ[4][4], sD[4][4], sM1[4][4], sM2[4][4], sZ1[4], sZ20[4];

  // ---- 1-deep software-pipelined streaming loop ----
  int c = tid;  // kC4 = 2500 > 256, so the prologue load is always in range
  float4 A = p1[c], Bv = p2[c], Cv = p3[c], Sv = ps[c];
  while (true) {
    const int cn = c + kNT;
    const bool last = (cn >= kC4);
    const int cl = last ? c : cn;  // clamped prefetch (redundant L1-hit on last)
    float4 nA = p1[cl];
    float4 nB = p2[cl];
    float4 nC = p3[cl];
    float4 nS = ps[cl];

    float va[4] = {A.x, A.y, A.z, A.w};
    float vb[4] = {Bv.x, Bv.y, Bv.z, Bv.w};
    float vc[4] = {Cv.x, Cv.y, Cv.z, Cv.w};
    float vs[4] = {Sv.x, Sv.y, Sv.z, Sv.w};
#pragma unroll
    for (int j = 0; j < 4; j++) {
      const float mim = (va[j] + vb[j] + vc[j]) * (1.0f / 3.0f);
      const float tv[4] = {va[j], vb[j], vc[j], mim};
      const float sv = vs[j];
#pragma unroll
      for (int t = 0; t < 4; t++) {
        const float x = tv[t];
        // branchless top-2 update
        const float lo = fminf(x, m1[t]);
        m1[t] = fmaxf(x, m1[t]);
        m2[t] = fmaxf(m2[t], lo);
        // inputs are N(0,1): exp(x/20) cannot overflow; no max subtraction needed
        const float e = __expf(x * 0.05f);
        Z[t] += e;
        D[t] = fmaf(e, sv, D[t]);
      }
      Z1 += __expf(sv);
      Z20 += __expf(sv * 0.05f);
    }

    if (last) break;
    c = cn;
    A = nA; Bv = nB; Cv = nC; Sv = nS;
  }

  // wave-level reductions
#pragma unroll
  for (int t = 0; t < 4; t++) {
    Z[t] = wave_sum(Z[t]);
    D[t] = wave_sum(D[t]);
    wave_top2(m1[t], m2[t]);
  }
  Z1 = wave_sum(Z1);
  Z20 = wave_sum(Z20);

  if (lane == 0) {
#pragma unroll
    for (int t = 0; t < 4; t++) {
      sZ[t][wv] = Z[t]; sD[t][wv] = D[t];
      sM1[t][wv] = m1[t]; sM2[t][wv] = m2[t];
    }
    sZ1[wv] = Z1; sZ20[wv] = Z20;
  }
  __syncthreads();

  if (tid == 0) {
    float fZ[4], fD[4], fM1[4], fM2[4];
    float fZ1 = 0.f, fZ20 = 0.f;
#pragma unroll
    for (int t = 0; t < 4; t++) { fZ[t] = 0.f; fD[t] = 0.f; fM1[t] = -1e30f; fM2[t] = -1e30f; }
#pragma unroll
    for (int w = 0; w < 4; w++) {
      fZ1 += sZ1[w]; fZ20 += sZ20[w];
#pragma unroll
      for (int t = 0; t < 4; t++) {
        fZ[t] += sZ[t][w];
        fD[t] += sD[t][w];
        const float a1 = sM1[t][w], a2 = sM2[t][w];
        const float lo = fminf(fM1[t], a1);
        fM1[t] = fmaxf(fM1[t], a1);
        fM2[t] = fmaxf(lo, fmaxf(fM2[t], a2));
      }
    }

    // mimic target value computed with the exact same expression as in-loop
    const float tvm = (tv1 + tv2 + tv3) * (1.0f / 3.0f);
    const float tval[4] = {tv1, tv2, tv3, tvm};

    const float ce = logf(fZ1) - tvs;         // logsumexp(out_s) - out_s[target]
    const float lz20 = logf(fZ20);            // log sum exp(out_s/20)

    float d[4], kd[4];
#pragma unroll
    for (int t = 0; t < 4; t++) {
      // kd = T^2 * ( logZ_s20 - (sum_c p_c * s_c)/T ),  p from teacher softmax at T=20
      kd[t] = 400.0f * (lz20 - fD[t] / (20.0f * fZ[t]));
      d[t] = (tval[t] == fM1[t]) ? (fM1[t] - fM2[t]) : 0.0f;
    }
    // out_threshold = softmax(d / 2)
    float ew[4], se = 0.f;
#pragma unroll
    for (int t = 0; t < 4; t++) { ew[t] = __expf(d[t] * 0.5f); se += ew[t]; }
    float rowB = 0.f;
#pragma unroll
    for (int t = 0; t < 4; t++) rowB += (ew[t] / se) * tval[t] * (kd[t] - ce);

    ceArr[b] = ce;
    bArr[b] = rowB;
    mArr[b] = fmaxf(fM1[0], fmaxf(fM1[1], fM1[2]));  // real teachers only
  }
}

// Single-block reduction of the 3 per-row arrays -> scalar output.
__global__ __launch_bounds__(256) void mt3_finalize(
    const float* __restrict__ ceArr, const float* __restrict__ bArr,
    const float* __restrict__ mArr, float* __restrict__ out) {
  const int tid = threadIdx.x;
  const int lane = tid & 63;
  const int wv = tid >> 6;

  double sc = 0.0, sb = 0.0;
  float mx = -1e30f;
  for (int i = tid; i < kB; i += 256) {
    sc += (double)ceArr[i];
    sb += (double)bArr[i];
    mx = fmaxf(mx, mArr[i]);
  }
  sc = wave_sum_d(sc);
  sb = wave_sum_d(sb);
  mx = wave_max(mx);

  __shared__ double dsc[4], dsb[4];
  __shared__ float dmx[4];
  if (lane == 0) { dsc[wv] = sc; dsb[wv] = sb; dmx[wv] = mx; }
  __syncthreads();
  if (tid == 0) {
    double A = 0.0, Bc = 0.0;
    float M = -1e30f;
#pragma unroll
    for (int w = 0; w < 4; w++) { A += dsc[w]; Bc += dsb[w]; M = fmaxf(M, dmx[w]); }
    // mean(ce) + (alpha/max_preds) * mean(rowB)
    out[0] = (float)((A + 0.8 * Bc / (double)M) / (double)kB);
  }
}

extern "C" void kernel_launch(void* const* d_in, const int* in_sizes, int n_in,
                              void* d_out, int out_size, void* d_ws, size_t ws_size,
                              hipStream_t stream) {
  const float* o1 = (const float*)d_in[0];
  const float* o2 = (const float*)d_in[1];
  const float* o3 = (const float*)d_in[2];
  const float* os = (const float*)d_in[3];
  const int* tg = (const int*)d_in[4];

  float* ws = (float*)d_ws;
  float* ceArr = ws;            // [kB]
  float* bArr = ws + kB;        // [kB]
  float* mArr = ws + 2 * kB;    // [kB]

  mt3_row_kernel<<<kB, kNT, 0, stream>>>(o1, o2, o3, os, tg, ceArr, bArr, mArr);
  mt3_finalize<<<1, 256, 0, stream>>>(ceArr, bArr, mArr, (float*)d_out);
}

// Round 3
// 513.056 us; speedup vs baseline: 1.0143x; 1.0083x over previous
//
#include <hip/hip_runtime.h>

namespace {
constexpr int kB = 4096;
constexpr int kC = 10000;
constexpr int kC4 = kC / 4;   // 2500 float4 chunks per row
constexpr int kNT = 256;      // threads per block
}

// ---------- wave(64)-level helpers ----------
__device__ __forceinline__ float wave_sum(float v) {
#pragma unroll
  for (int o = 32; o > 0; o >>= 1) v += __shfl_down(v, o, 64);
  return v;
}

__device__ __forceinline__ double wave_sum_d(double v) {
#pragma unroll
  for (int o = 32; o > 0; o >>= 1) v += __shfl_down(v, o, 64);
  return v;
}

__device__ __forceinline__ float wave_max(float v) {
#pragma unroll
  for (int o = 32; o > 0; o >>= 1) v = fmaxf(v, __shfl_down(v, o, 64));
  return v;
}

// merge top-2 pairs across a wave
__device__ __forceinline__ void wave_top2(float& m1, float& m2) {
#pragma unroll
  for (int o = 32; o > 0; o >>= 1) {
    float a1 = __shfl_down(m1, o, 64);
    float a2 = __shfl_down(m2, o, 64);
    float lo = fminf(m1, a1);
    m1 = fmaxf(m1, a1);
    m2 = fmaxf(lo, fmaxf(m2, a2));
  }
}

struct Chunk {  // one float4 from each of the 4 arrays
  float4 a, b, c, s;
};

// One block per sample row. 2-deep software pipeline: while computing chunk c,
// loads for c+256 and c+512 are in flight (8 x dwordx4 = 8KB/wave outstanding).
__global__ __launch_bounds__(kNT) void mt3_row_kernel(
    const float* __restrict__ g1, const float* __restrict__ g2,
    const float* __restrict__ g3, const float* __restrict__ gs,
    const int* __restrict__ gt,
    float* __restrict__ ceArr, float* __restrict__ bArr,
    float* __restrict__ mArr) {
  const int b = blockIdx.x;
  const int tid = threadIdx.x;
  const int lane = tid & 63;
  const int wv = tid >> 6;  // 4 waves

  const size_t rowOff = (size_t)b * kC;
  const float4* __restrict__ p1 = reinterpret_cast<const float4*>(g1 + rowOff);
  const float4* __restrict__ p2 = reinterpret_cast<const float4*>(g2 + rowOff);
  const float4* __restrict__ p3 = reinterpret_cast<const float4*>(g3 + rowOff);
  const float4* __restrict__ ps = reinterpret_cast<const float4*>(gs + rowOff);

  const int target = gt[b];

  // Target-column values: loaded once (bitwise-identical to streamed values,
  // so the "tval == rowmax" comparison is exact). Issued early, used at end.
  float tv1 = 0.f, tv2 = 0.f, tv3 = 0.f, tvs = 0.f;
  if (tid == 0) {
    tv1 = g1[rowOff + target];
    tv2 = g2[rowOff + target];
    tv3 = g3[rowOff + target];
    tvs = gs[rowOff + target];
  }

  // per-teacher state: 0..2 real teachers, 3 = mimic
  float m1[4], m2[4], Z[4], D[4];
#pragma unroll
  for (int t = 0; t < 4; t++) { m1[t] = -1e30f; m2[t] = -1e30f; Z[t] = 0.f; D[t] = 0.f; }
  float Z1 = 0.f;   // sum exp(s)      (T=1, for CE logsumexp)
  float Z20 = 0.f;  // sum exp(s/20)   (T=20, for KD logsumexp)

  __shared__ float sZ[4][4], sD[4][4], sM1[4][4], sM2[4][4], sZ1[4], sZ20[4];

  // ---- 2-deep pipelined streaming loop ----
  // A0 = data for chunk c (being computed), A1 = c+256 (in flight/held),
  // A2 = c+512 (issued this iteration).
  int c = tid;  // tid < 256 << 2500, so first two loads are always in range
  Chunk A0, A1, A2;
  A0.a = p1[c];        A0.b = p2[c];        A0.c = p3[c];        A0.s = ps[c];
  A1.a = p1[c + kNT];  A1.b = p2[c + kNT];  A1.c = p3[c + kNT];  A1.s = ps[c + kNT];

  while (true) {
    const int cn2 = c + 2 * kNT;
    const int idx2 = (cn2 < kC4) ? cn2 : c;  // clamped (redundant load on tail)
    A2.a = p1[idx2];
    A2.b = p2[idx2];
    A2.c = p3[idx2];
    A2.s = ps[idx2];

    const float va[4] = {A0.a.x, A0.a.y, A0.a.z, A0.a.w};
    const float vb[4] = {A0.b.x, A0.b.y, A0.b.z, A0.b.w};
    const float vc[4] = {A0.c.x, A0.c.y, A0.c.z, A0.c.w};
    const float vs[4] = {A0.s.x, A0.s.y, A0.s.z, A0.s.w};
#pragma unroll
    for (int j = 0; j < 4; j++) {
      const float mim = (va[j] + vb[j] + vc[j]) * (1.0f / 3.0f);
      const float tv[4] = {va[j], vb[j], vc[j], mim};
      const float sv = vs[j];
#pragma unroll
      for (int t = 0; t < 4; t++) {
        const float x = tv[t];
        // branchless top-2 update
        const float lo = fminf(x, m1[t]);
        m1[t] = fmaxf(x, m1[t]);
        m2[t] = fmaxf(m2[t], lo);
        // inputs are N(0,1): exp(x/20) cannot overflow; no max subtraction
        const float e = __expf(x * 0.05f);
        Z[t] += e;
        D[t] = fmaf(e, sv, D[t]);
      }
      Z1 += __expf(sv);
      Z20 += __expf(sv * 0.05f);
    }

    if (c + kNT >= kC4) break;  // A1/A2 beyond this are clamped duplicates
    c += kNT;
    A0 = A1;
    A1 = A2;
  }

  // wave-level reductions
#pragma unroll
  for (int t = 0; t < 4; t++) {
    Z[t] = wave_sum(Z[t]);
    D[t] = wave_sum(D[t]);
    wave_top2(m1[t], m2[t]);
  }
  Z1 = wave_sum(Z1);
  Z20 = wave_sum(Z20);

  if (lane == 0) {
#pragma unroll
    for (int t = 0; t < 4; t++) {
      sZ[t][wv] = Z[t]; sD[t][wv] = D[t];
      sM1[t][wv] = m1[t]; sM2[t][wv] = m2[t];
    }
    sZ1[wv] = Z1; sZ20[wv] = Z20;
  }
  __syncthreads();

  if (tid == 0) {
    float fZ[4], fD[4], fM1[4], fM2[4];
    float fZ1 = 0.f, fZ20 = 0.f;
#pragma unroll
    for (int t = 0; t < 4; t++) { fZ[t] = 0.f; fD[t] = 0.f; fM1[t] = -1e30f; fM2[t] = -1e30f; }
#pragma unroll
    for (int w = 0; w < 4; w++) {
      fZ1 += sZ1[w]; fZ20 += sZ20[w];
#pragma unroll
      for (int t = 0; t < 4; t++) {
        fZ[t] += sZ[t][w];
        fD[t] += sD[t][w];
        const float a1 = sM1[t][w], a2 = sM2[t][w];
        const float lo = fminf(fM1[t], a1);
        fM1[t] = fmaxf(fM1[t], a1);
        fM2[t] = fmaxf(lo, fmaxf(fM2[t], a2));
      }
    }

    // mimic target value: exact same expression as in-loop
    const float tvm = (tv1 + tv2 + tv3) * (1.0f / 3.0f);
    const float tval[4] = {tv1, tv2, tv3, tvm};

    const float ce = logf(fZ1) - tvs;         // logsumexp(out_s) - out_s[target]
    const float lz20 = logf(fZ20);            // log sum exp(out_s/20)

    float d[4], kd[4];
#pragma unroll
    for (int t = 0; t < 4; t++) {
      // kd = T^2 * ( logZ_s20 - (sum_c p_c * s_c)/T ),  p = teacher softmax @T=20
      kd[t] = 400.0f * (lz20 - fD[t] / (20.0f * fZ[t]));
      d[t] = (tval[t] == fM1[t]) ? (fM1[t] - fM2[t]) : 0.0f;
    }
    // out_threshold = softmax(d / 2)
    float ew[4], se = 0.f;
#pragma unroll
    for (int t = 0; t < 4; t++) { ew[t] = __expf(d[t] * 0.5f); se += ew[t]; }
    float rowB = 0.f;
#pragma unroll
    for (int t = 0; t < 4; t++) rowB += (ew[t] / se) * tval[t] * (kd[t] - ce);

    ceArr[b] = ce;
    bArr[b] = rowB;
    mArr[b] = fmaxf(fM1[0], fmaxf(fM1[1], fM1[2]));  // real teachers only
  }
}

// Single-block reduction of the 3 per-row arrays -> scalar output.
__global__ __launch_bounds__(256) void mt3_finalize(
    const float* __restrict__ ceArr, const float* __restrict__ bArr,
    const float* __restrict__ mArr, float* __restrict__ out) {
  const int tid = threadIdx.x;
  const int lane = tid & 63;
  const int wv = tid >> 6;

  double sc = 0.0, sb = 0.0;
  float mx = -1e30f;
  for (int i = tid; i < kB; i += 256) {
    sc += (double)ceArr[i];
    sb += (double)bArr[i];
    mx = fmaxf(mx, mArr[i]);
  }
  sc = wave_sum_d(sc);
  sb = wave_sum_d(sb);
  mx = wave_max(mx);

  __shared__ double dsc[4], dsb[4];
  __shared__ float dmx[4];
  if (lane == 0) { dsc[wv] = sc; dsb[wv] = sb; dmx[wv] = mx; }
  __syncthreads();
  if (tid == 0) {
    double A = 0.0, Bc = 0.0;
    float M = -1e30f;
#pragma unroll
    for (int w = 0; w < 4; w++) { A += dsc[w]; Bc += dsb[w]; M = fmaxf(M, dmx[w]); }
    // mean(ce) + (alpha/max_preds) * mean(rowB)
    out[0] = (float)((A + 0.8 * Bc / (double)M) / (double)kB);
  }
}

extern "C" void kernel_launch(void* const* d_in, const int* in_sizes, int n_in,
                              void* d_out, int out_size, void* d_ws, size_t ws_size,
                              hipStream_t stream) {
  const float* o1 = (const float*)d_in[0];
  const float* o2 = (const float*)d_in[1];
  const float* o3 = (const float*)d_in[2];
  const float* os = (const float*)d_in[3];
  const int* tg = (const int*)d_in[4];

  float* ws = (float*)d_ws;
  float* ceArr = ws;            // [kB]
  float* bArr = ws + kB;        // [kB]
  float* mArr = ws + 2 * kB;    // [kB]

  mt3_row_kernel<<<kB, kNT, 0, stream>>>(o1, o2, o3, os, tg, ceArr, bArr, mArr);
  mt3_finalize<<<1, 256, 0, stream>>>(ceArr, bArr, mArr, (float*)d_out);
}